// Round 2
// baseline (2170.415 us; speedup 1.0000x reference)
//
#include <hip/hip_runtime.h>

#define NU 500000
#define NI 200000
#define NN (NU + NI)         // combined node count (users then items)
#define NE 2000000
#define HD 32
#define DF 256
#define OC 96                // output row stride = 3*H

__device__ __forceinline__ float lrelu(float v){ return v >= 0.f ? v : 0.01f*v; }
__device__ __forceinline__ float4 f4add(float4 a, float4 b){
  return make_float4(a.x+b.x, a.y+b.y, a.z+b.z, a.w+b.w);
}

__global__ void k_zero_i32(int* __restrict__ p, int n){
  int i = blockIdx.x*blockDim.x + threadIdx.x;
  if (i < n) p[i] = 0;
}

// final_user[:,0:32] = user_emb[user_ids]  (cols 32:96 written later by pull_fin)
__global__ void k_init_user(const int* __restrict__ ids, const float* __restrict__ emb,
                            float* __restrict__ outu){
  int i = blockIdx.x*blockDim.x + threadIdx.x;
  if (i >= NU) return;
  int uid = ids[i];
  const float4* s = (const float4*)(emb + (size_t)uid*HD);
  float4* d = (float4*)(outu + (size_t)i*OC);
  #pragma unroll
  for (int q = 0; q < 8; ++q) d[q] = s[q];
}

// final_item[:,0:32] = item_emb[product_ids] + feat @ W^T + b
// split-K: 512 threads, seg = wave-uniform K-half, combine via LDS (stride 34 to dodge banks)
__global__ __launch_bounds__(512) void k_init_item(
    const int* __restrict__ ids, const float* __restrict__ emb,
    const float* __restrict__ feat, const float* __restrict__ W,
    const float* __restrict__ bias, float* __restrict__ outi){
  __shared__ float combo[256*34];
  int t = threadIdx.x;
  int r = t & 255;
  int seg = __builtin_amdgcn_readfirstlane(t >> 8);   // 0 or 1, wave-uniform -> scalar W addr
  int row = blockIdx.x*256 + r;
  bool valid = row < NI;
  float acc[HD];
  #pragma unroll
  for (int h = 0; h < HD; ++h) acc[h] = 0.f;

  if (valid) {
    const float4* f4 = (const float4*)(feat + (size_t)row*DF + seg*128);
    float4 a0 = f4[0], a1 = f4[1];
    for (int k0 = 0; k0 < 128; k0 += 8) {
      float4 n0 = make_float4(0,0,0,0), n1 = n0;
      if (k0 + 8 < 128) { n0 = f4[(k0>>2)+2]; n1 = f4[(k0>>2)+3]; }
      float fv[8] = {a0.x,a0.y,a0.z,a0.w,a1.x,a1.y,a1.z,a1.w};
      #pragma unroll
      for (int kk = 0; kk < 8; ++kk) {
        #pragma unroll
        for (int h = 0; h < HD; ++h)
          acc[h] += fv[kk]*W[h*DF + seg*128 + k0 + kk];   // scalar (s_load) operand
      }
      a0 = n0; a1 = n1;
    }
  }
  // seg1 -> LDS
  if (seg == 1) {
    float2* c2 = (float2*)(combo + r*34);
    #pragma unroll
    for (int q = 0; q < 16; ++q) c2[q] = make_float2(acc[2*q], acc[2*q+1]);
  }
  __syncthreads();
  if (seg == 0 && valid) {
    const float2* c2 = (const float2*)(combo + r*34);
    #pragma unroll
    for (int q = 0; q < 16; ++q) { float2 v = c2[q]; acc[2*q] += v.x; acc[2*q+1] += v.y; }
    int pid = ids[row];
    const float4* ev = (const float4*)(emb + (size_t)pid*HD);
    const float4* bv = (const float4*)bias;
    float4* dst = (float4*)(outi + (size_t)row*OC);
    #pragma unroll
    for (int q = 0; q < 8; ++q) {
      float4 e = ev[q], b = bv[q];
      dst[q] = make_float4(acc[4*q+0]+e.x+b.x, acc[4*q+1]+e.y+b.y,
                           acc[4*q+2]+e.z+b.z, acc[4*q+3]+e.w+b.w);
    }
  }
}

// degree histogram over combined node ids (users 0..NU-1, items NU..NN-1)
__global__ void k_deg(const int* __restrict__ esrc, const int* __restrict__ edst,
                      int* __restrict__ cnt){
  int e = blockIdx.x*blockDim.x + threadIdx.x;
  if (e >= NE) return;
  atomicAdd(cnt + esrc[e], 1);        // user side
  atomicAdd(cnt + NU + edst[e], 1);   // item side
}

// ---- 3-kernel exclusive scan over cnt[NN] -> off[NN] ----
__global__ void k_scan1(const int* __restrict__ cnt, int* __restrict__ off,
                        int* __restrict__ part, int n){
  __shared__ int s[256];
  int t = threadIdx.x, i = blockIdx.x*256 + t;
  int v = (i < n) ? cnt[i] : 0;
  s[t] = v; __syncthreads();
  for (int o = 1; o < 256; o <<= 1) {
    int x = (t >= o) ? s[t-o] : 0;
    __syncthreads(); s[t] += x; __syncthreads();
  }
  if (i < n) off[i] = s[t] - v;
  if (t == 255) part[blockIdx.x] = s[255];
}

__global__ void k_scan2(int* __restrict__ part, int nb){
  __shared__ int s[256];
  __shared__ int carry;
  int t = threadIdx.x;
  if (t == 0) carry = 0;
  __syncthreads();
  for (int c0 = 0; c0 < nb; c0 += 256) {
    int i = c0 + t;
    int v = (i < nb) ? part[i] : 0;
    s[t] = v; __syncthreads();
    for (int o = 1; o < 256; o <<= 1) {
      int x = (t >= o) ? s[t-o] : 0;
      __syncthreads(); s[t] += x; __syncthreads();
    }
    int total = s[255];
    if (i < nb) part[i] = carry + s[t] - v;
    __syncthreads();
    if (t == 0) carry += total;
    __syncthreads();
  }
}

__global__ void k_scan3(int* __restrict__ off, const int* __restrict__ part, int n){
  int i = blockIdx.x*256 + threadIdx.x;
  if (i < n) off[i] += part[blockIdx.x];
}

// scatter edges into CSR neighbor lists (order nondeterministic; sums threshold-safe)
__global__ void k_scatter(const int* __restrict__ esrc, const int* __restrict__ edst,
                          const int* __restrict__ off, int* __restrict__ cur,
                          int* __restrict__ nbr){
  int e = blockIdx.x*blockDim.x + threadIdx.x;
  if (e >= NE) return;
  int u = esrc[e], p = edst[e];
  int s1 = off[u]      + atomicAdd(cur + u,      1); nbr[s1] = p;  // user's item list
  int s2 = off[NU + p] + atomicAdd(cur + NU + p, 1); nbr[s2] = u;  // item's user list
}

// Fused pull-aggregate + SAGE linear + leakyReLU.
// 4 threads per dst node, 8 h-channels each; allgather m/x via shfl_xor(1,2).
__global__ void k_pull_fin(float* __restrict__ dstbase, int n, int nodebase,
                           const float* __restrict__ srcbase, int soff, int xoff, int outoff,
                           const int* __restrict__ off, const int* __restrict__ cnt,
                           const int* __restrict__ nbr,
                           const float* __restrict__ Wl, const float* __restrict__ bl,
                           const float* __restrict__ Wr){
  int tid = blockIdx.x*256 + threadIdx.x;
  int node = tid >> 2;
  if (node >= n) return;
  int q = tid & 3;
  int gnode = nodebase + node;
  int deg = cnt[gnode];
  int start = off[gnode];

  float4 acc0 = make_float4(0,0,0,0), acc1 = acc0;
  for (int j = 0; j < deg; ++j) {
    int s = nbr[start + j];
    const float4* sr = (const float4*)(srcbase + (size_t)s*OC + soff + q*8);
    acc0 = f4add(acc0, sr[0]);
    acc1 = f4add(acc1, sr[1]);
  }
  float inv = 1.f / (float)(deg < 1 ? 1 : deg);
  float m0[8] = {acc0.x*inv, acc0.y*inv, acc0.z*inv, acc0.w*inv,
                 acc1.x*inv, acc1.y*inv, acc1.z*inv, acc1.w*inv};
  const float4* xr = (const float4*)(dstbase + (size_t)node*OC + xoff + q*8);
  float4 xv0 = xr[0], xv1 = xr[1];
  float x0[8] = {xv0.x,xv0.y,xv0.z,xv0.w,xv1.x,xv1.y,xv1.z,xv1.w};

  // allgather 8 -> 32 within the 4-thread group
  bool hi1 = (q & 1), hi2 = (q & 2);
  float tm[16], tx[16];
  #pragma unroll
  for (int k = 0; k < 8; ++k) {
    float om = __shfl_xor(m0[k], 1), ox = __shfl_xor(x0[k], 1);
    tm[k]   = hi1 ? om    : m0[k];  tx[k]   = hi1 ? ox    : x0[k];
    tm[k+8] = hi1 ? m0[k] : om;     tx[k+8] = hi1 ? x0[k] : ox;
  }
  float m[32], x[32];
  #pragma unroll
  for (int k = 0; k < 16; ++k) {
    float om = __shfl_xor(tm[k], 2), ox = __shfl_xor(tx[k], 2);
    m[k]    = hi2 ? om    : tm[k];  x[k]    = hi2 ? ox    : tx[k];
    m[k+16] = hi2 ? tm[k] : om;     x[k+16] = hi2 ? tx[k] : ox;
  }

  float y[8];
  #pragma unroll
  for (int k = 0; k < 8; ++k) {
    int h = q*8 + k;
    float s = bl[h];
    const float4* wl = (const float4*)(Wl + h*HD);
    const float4* wr = (const float4*)(Wr + h*HD);
    #pragma unroll
    for (int j4 = 0; j4 < 8; ++j4) {
      float4 wv = wl[j4];
      s += m[4*j4+0]*wv.x + m[4*j4+1]*wv.y + m[4*j4+2]*wv.z + m[4*j4+3]*wv.w;
    }
    #pragma unroll
    for (int j4 = 0; j4 < 8; ++j4) {
      float4 wv = wr[j4];
      s += x[4*j4+0]*wv.x + x[4*j4+1]*wv.y + x[4*j4+2]*wv.z + x[4*j4+3]*wv.w;
    }
    y[k] = lrelu(s);
  }
  float4* orow = (float4*)(dstbase + (size_t)node*OC + outoff + q*8);
  orow[0] = make_float4(y[0],y[1],y[2],y[3]);
  orow[1] = make_float4(y[4],y[5],y[6],y[7]);
}

extern "C" void kernel_launch(void* const* d_in, const int* in_sizes, int n_in,
                              void* d_out, int out_size, void* d_ws, size_t ws_size,
                              hipStream_t stream) {
  const int*   user_ids = (const int*)d_in[0];
  const int*   prod_ids = (const int*)d_in[1];
  const float* feat     = (const float*)d_in[2];
  const int*   er       = (const int*)d_in[3];   // [2, NE]: row0 = user(src), row1 = item(dst)
  const float* uemb     = (const float*)d_in[5];
  const float* iemb     = (const float*)d_in[6];
  const float* fW       = (const float*)d_in[7];
  const float* fb       = (const float*)d_in[8];
  const float* Wl_up1 = (const float*)d_in[9];
  const float* bl_up1 = (const float*)d_in[10];
  const float* Wr_up1 = (const float*)d_in[11];
  const float* Wl_pu1 = (const float*)d_in[12];
  const float* bl_pu1 = (const float*)d_in[13];
  const float* Wr_pu1 = (const float*)d_in[14];
  const float* Wl_up2 = (const float*)d_in[15];
  const float* bl_up2 = (const float*)d_in[16];
  const float* Wr_up2 = (const float*)d_in[17];
  const float* Wl_pu2 = (const float*)d_in[18];
  const float* bl_pu2 = (const float*)d_in[19];
  const float* Wr_pu2 = (const float*)d_in[20];

  float* outu = (float*)d_out;
  float* outi = outu + (size_t)NU*OC;

  // workspace layout (ints): cnt[NN] | cur[NN] | off[NN] | part[2736] | nbr[2*NE]
  int* cnt  = (int*)d_ws;
  int* cur  = cnt + NN;
  int* off  = cur + NN;
  int* part = off + NN;
  int* nbr  = part + 2736;

  const int* er_src = er;        // users
  const int* er_dst = er + NE;   // items

  const int B = 256;
  const int NB1 = (NN + 255)/256;   // 2735 scan blocks

  k_zero_i32<<<(2*NN + B - 1)/B, B, 0, stream>>>(cnt, 2*NN);  // cnt + cur contiguous
  k_deg<<<(NE + B - 1)/B, B, 0, stream>>>(er_src, er_dst, cnt);
  k_scan1<<<NB1, B, 0, stream>>>(cnt, off, part, NN);
  k_scan2<<<1, B, 0, stream>>>(part, NB1);
  k_scan3<<<NB1, B, 0, stream>>>(off, part, NN);
  k_scatter<<<(NE + B - 1)/B, B, 0, stream>>>(er_src, er_dst, off, cur, nbr);

  k_init_user<<<(NU + B - 1)/B, B, 0, stream>>>(user_ids, uemb, outu);
  k_init_item<<<(NI + 255)/256, 512, 0, stream>>>(prod_ids, iemb, feat, fW, fb, outi);

  // layer 1: items pull users(xu), users pull items(xp)
  k_pull_fin<<<(NI*4 + B - 1)/B, B, 0, stream>>>(outi, NI, NU, outu, 0, 0, 32,
                                                 off, cnt, nbr, Wl_up1, bl_up1, Wr_up1);
  k_pull_fin<<<(NU*4 + B - 1)/B, B, 0, stream>>>(outu, NU, 0, outi, 0, 0, 32,
                                                 off, cnt, nbr, Wl_pu1, bl_pu1, Wr_pu1);
  // layer 2: items pull u1, users pull p1
  k_pull_fin<<<(NI*4 + B - 1)/B, B, 0, stream>>>(outi, NI, NU, outu, 32, 32, 64,
                                                 off, cnt, nbr, Wl_up2, bl_up2, Wr_up2);
  k_pull_fin<<<(NU*4 + B - 1)/B, B, 0, stream>>>(outu, NU, 0, outi, 32, 32, 64,
                                                 off, cnt, nbr, Wl_pu2, bl_pu2, Wr_pu2);
}

// Round 3
// 1966.786 us; speedup vs baseline: 1.1035x; 1.1035x over previous
//
#include <hip/hip_runtime.h>

#define NU 500000
#define NI 200000
#define NN (NU + NI)         // combined node count (users then items)
#define NE 2000000
#define HD 32
#define DF 256
#define OC 96                // output row stride = 3*H

__device__ __forceinline__ float lrelu(float v){ return v >= 0.f ? v : 0.01f*v; }
__device__ __forceinline__ float4 f4add(float4 a, float4 b){
  return make_float4(a.x+b.x, a.y+b.y, a.z+b.z, a.w+b.w);
}

__global__ void k_zero_i32(int* __restrict__ p, int n){
  int i = blockIdx.x*blockDim.x + threadIdx.x;
  if (i < n) p[i] = 0;
}

// final_user[:,0:32] = user_emb[user_ids]
__global__ void k_init_user(const int* __restrict__ ids, const float* __restrict__ emb,
                            float* __restrict__ outu){
  int i = blockIdx.x*blockDim.x + threadIdx.x;
  if (i >= NU) return;
  int uid = ids[i];
  const float4* s = (const float4*)(emb + (size_t)uid*HD);
  float4* d = (float4*)(outu + (size_t)i*OC);
  #pragma unroll
  for (int q = 0; q < 8; ++q) d[q] = s[q];
}

// final_item[:,0:32] = item_emb[product_ids] + feat @ W^T + b
// split-K: 512 threads, seg = wave-uniform K-half, combine via LDS
__global__ __launch_bounds__(512) void k_init_item(
    const int* __restrict__ ids, const float* __restrict__ emb,
    const float* __restrict__ feat, const float* __restrict__ W,
    const float* __restrict__ bias, float* __restrict__ outi){
  __shared__ float combo[256*34];
  int t = threadIdx.x;
  int r = t & 255;
  int seg = __builtin_amdgcn_readfirstlane(t >> 8);   // 0 or 1, wave-uniform
  int row = blockIdx.x*256 + r;
  bool valid = row < NI;
  float acc[HD];
  #pragma unroll
  for (int h = 0; h < HD; ++h) acc[h] = 0.f;

  if (valid) {
    const float4* f4 = (const float4*)(feat + (size_t)row*DF + seg*128);
    float4 a0 = f4[0], a1 = f4[1];
    for (int k0 = 0; k0 < 128; k0 += 8) {
      float4 n0 = make_float4(0,0,0,0), n1 = n0;
      if (k0 + 8 < 128) { n0 = f4[(k0>>2)+2]; n1 = f4[(k0>>2)+3]; }
      float fv[8] = {a0.x,a0.y,a0.z,a0.w,a1.x,a1.y,a1.z,a1.w};
      #pragma unroll
      for (int kk = 0; kk < 8; ++kk) {
        #pragma unroll
        for (int h = 0; h < HD; ++h)
          acc[h] += fv[kk]*W[h*DF + seg*128 + k0 + kk];   // scalar (s_load) operand
      }
      a0 = n0; a1 = n1;
    }
  }
  if (seg == 1) {
    float2* c2 = (float2*)(combo + r*34);
    #pragma unroll
    for (int q = 0; q < 16; ++q) c2[q] = make_float2(acc[2*q], acc[2*q+1]);
  }
  __syncthreads();
  if (seg == 0 && valid) {
    const float2* c2 = (const float2*)(combo + r*34);
    #pragma unroll
    for (int q = 0; q < 16; ++q) { float2 v = c2[q]; acc[2*q] += v.x; acc[2*q+1] += v.y; }
    int pid = ids[row];
    const float4* ev = (const float4*)(emb + (size_t)pid*HD);
    const float4* bv = (const float4*)bias;
    float4* dst = (float4*)(outi + (size_t)row*OC);
    #pragma unroll
    for (int q = 0; q < 8; ++q) {
      float4 e = ev[q], b = bv[q];
      dst[q] = make_float4(acc[4*q+0]+e.x+b.x, acc[4*q+1]+e.y+b.y,
                           acc[4*q+2]+e.z+b.z, acc[4*q+3]+e.w+b.w);
    }
  }
}

// degree histogram over combined node ids (users 0..NU-1, items NU..NN-1)
__global__ void k_deg(const int* __restrict__ esrc, const int* __restrict__ edst,
                      int* __restrict__ cnt){
  int e = blockIdx.x*blockDim.x + threadIdx.x;
  if (e >= NE) return;
  atomicAdd(cnt + esrc[e], 1);
  atomicAdd(cnt + NU + edst[e], 1);
}

// ---- 3-kernel exclusive scan over cnt[NN] -> off[NN] ----
__global__ void k_scan1(const int* __restrict__ cnt, int* __restrict__ off,
                        int* __restrict__ part, int n){
  __shared__ int s[256];
  int t = threadIdx.x, i = blockIdx.x*256 + t;
  int v = (i < n) ? cnt[i] : 0;
  s[t] = v; __syncthreads();
  for (int o = 1; o < 256; o <<= 1) {
    int x = (t >= o) ? s[t-o] : 0;
    __syncthreads(); s[t] += x; __syncthreads();
  }
  if (i < n) off[i] = s[t] - v;
  if (t == 255) part[blockIdx.x] = s[255];
}

__global__ void k_scan2(int* __restrict__ part, int nb){
  __shared__ int s[256];
  __shared__ int carry;
  int t = threadIdx.x;
  if (t == 0) carry = 0;
  __syncthreads();
  for (int c0 = 0; c0 < nb; c0 += 256) {
    int i = c0 + t;
    int v = (i < nb) ? part[i] : 0;
    s[t] = v; __syncthreads();
    for (int o = 1; o < 256; o <<= 1) {
      int x = (t >= o) ? s[t-o] : 0;
      __syncthreads(); s[t] += x; __syncthreads();
    }
    int total = s[255];
    if (i < nb) part[i] = carry + s[t] - v;
    __syncthreads();
    if (t == 0) carry += total;
    __syncthreads();
  }
}

__global__ void k_scan3(int* __restrict__ off, const int* __restrict__ part, int n){
  int i = blockIdx.x*256 + threadIdx.x;
  if (i < n) off[i] += part[blockIdx.x];
}

// scatter edges into CSR neighbor lists
__global__ void k_scatter(const int* __restrict__ esrc, const int* __restrict__ edst,
                          const int* __restrict__ off, int* __restrict__ cur,
                          int* __restrict__ nbr){
  int e = blockIdx.x*blockDim.x + threadIdx.x;
  if (e >= NE) return;
  int u = esrc[e], p = edst[e];
  int s1 = off[u]      + atomicAdd(cur + u,      1); nbr[s1] = p;
  int s2 = off[NU + p] + atomicAdd(cur + NU + p, 1); nbr[s2] = u;
}

// Fused pull-aggregate + SAGE linear + leakyReLU.
// 8 threads per dst node, 4 cols each; gather unrolled x4 (4 independent loads
// in flight); allgather 4->32 via shfl_xor(1,2,4) for the fused matvec.
__global__ void k_pull_fin(float* __restrict__ dstbase, int n, int nodebase,
                           const float* __restrict__ srcbase, int soff, int xoff, int outoff,
                           const int* __restrict__ off, const int* __restrict__ cnt,
                           const int* __restrict__ nbr,
                           const float* __restrict__ Wl, const float* __restrict__ bl,
                           const float* __restrict__ Wr){
  int tid = blockIdx.x*256 + threadIdx.x;
  int node = tid >> 3;
  if (node >= n) return;
  int q = tid & 7;                 // cols q*4 .. q*4+3
  int gnode = nodebase + node;
  int deg = cnt[gnode];
  int start = off[gnode];

  // x (root) slice — load early to overlap with gather
  float4 xv = *(const float4*)(dstbase + (size_t)node*OC + xoff + q*4);

  const float* sb = srcbase + soff + q*4;
  float4 z = make_float4(0,0,0,0);
  float4 a0 = z, a1 = z, a2 = z, a3 = z;
  int j = 0;
  for (; j + 4 <= deg; j += 4) {
    int s0 = nbr[start+j+0], s1 = nbr[start+j+1];
    int s2 = nbr[start+j+2], s3 = nbr[start+j+3];
    float4 r0 = *(const float4*)(sb + (size_t)s0*OC);
    float4 r1 = *(const float4*)(sb + (size_t)s1*OC);
    float4 r2 = *(const float4*)(sb + (size_t)s2*OC);
    float4 r3 = *(const float4*)(sb + (size_t)s3*OC);
    a0 = f4add(a0, r0); a1 = f4add(a1, r1);
    a2 = f4add(a2, r2); a3 = f4add(a3, r3);
  }
  for (; j < deg; ++j) {
    int s = nbr[start+j];
    a0 = f4add(a0, *(const float4*)(sb + (size_t)s*OC));
  }
  a0 = f4add(f4add(a0, a1), f4add(a2, a3));
  float inv = 1.f / (float)(deg < 1 ? 1 : deg);
  float m0[4] = {a0.x*inv, a0.y*inv, a0.z*inv, a0.w*inv};
  float x0[4] = {xv.x, xv.y, xv.z, xv.w};

  // allgather 4 -> 32 across the 8-thread group
  bool b1 = (q & 1), b2 = (q & 2), b4 = (q & 4);
  float tm1[8], tx1[8];
  #pragma unroll
  for (int k = 0; k < 4; ++k) {
    float om = __shfl_xor(m0[k], 1), ox = __shfl_xor(x0[k], 1);
    tm1[k]   = b1 ? om    : m0[k];  tx1[k]   = b1 ? ox    : x0[k];
    tm1[k+4] = b1 ? m0[k] : om;     tx1[k+4] = b1 ? x0[k] : ox;
  }
  float tm2[16], tx2[16];
  #pragma unroll
  for (int k = 0; k < 8; ++k) {
    float om = __shfl_xor(tm1[k], 2), ox = __shfl_xor(tx1[k], 2);
    tm2[k]   = b2 ? om     : tm1[k];  tx2[k]   = b2 ? ox     : tx1[k];
    tm2[k+8] = b2 ? tm1[k] : om;      tx2[k+8] = b2 ? tx1[k] : ox;
  }
  float m[32], x[32];
  #pragma unroll
  for (int k = 0; k < 16; ++k) {
    float om = __shfl_xor(tm2[k], 4), ox = __shfl_xor(tx2[k], 4);
    m[k]    = b4 ? om     : tm2[k];  x[k]    = b4 ? ox     : tx2[k];
    m[k+16] = b4 ? tm2[k] : om;      x[k+16] = b4 ? tx2[k] : ox;
  }

  // y[h] for h = q*4 .. q*4+3
  float y[4];
  #pragma unroll
  for (int k = 0; k < 4; ++k) {
    int h = q*4 + k;
    float s = bl[h];
    const float4* wl = (const float4*)(Wl + h*HD);
    const float4* wr = (const float4*)(Wr + h*HD);
    #pragma unroll
    for (int j4 = 0; j4 < 8; ++j4) {
      float4 wv = wl[j4];
      s += m[4*j4+0]*wv.x + m[4*j4+1]*wv.y + m[4*j4+2]*wv.z + m[4*j4+3]*wv.w;
    }
    #pragma unroll
    for (int j4 = 0; j4 < 8; ++j4) {
      float4 wv = wr[j4];
      s += x[4*j4+0]*wv.x + x[4*j4+1]*wv.y + x[4*j4+2]*wv.z + x[4*j4+3]*wv.w;
    }
    y[k] = lrelu(s);
  }
  *(float4*)(dstbase + (size_t)node*OC + outoff + q*4) = make_float4(y[0],y[1],y[2],y[3]);
}

extern "C" void kernel_launch(void* const* d_in, const int* in_sizes, int n_in,
                              void* d_out, int out_size, void* d_ws, size_t ws_size,
                              hipStream_t stream) {
  const int*   user_ids = (const int*)d_in[0];
  const int*   prod_ids = (const int*)d_in[1];
  const float* feat     = (const float*)d_in[2];
  const int*   er       = (const int*)d_in[3];   // [2, NE]: row0 = user, row1 = item
  const float* uemb     = (const float*)d_in[5];
  const float* iemb     = (const float*)d_in[6];
  const float* fW       = (const float*)d_in[7];
  const float* fb       = (const float*)d_in[8];
  const float* Wl_up1 = (const float*)d_in[9];
  const float* bl_up1 = (const float*)d_in[10];
  const float* Wr_up1 = (const float*)d_in[11];
  const float* Wl_pu1 = (const float*)d_in[12];
  const float* bl_pu1 = (const float*)d_in[13];
  const float* Wr_pu1 = (const float*)d_in[14];
  const float* Wl_up2 = (const float*)d_in[15];
  const float* bl_up2 = (const float*)d_in[16];
  const float* Wr_up2 = (const float*)d_in[17];
  const float* Wl_pu2 = (const float*)d_in[18];
  const float* bl_pu2 = (const float*)d_in[19];
  const float* Wr_pu2 = (const float*)d_in[20];

  float* outu = (float*)d_out;
  float* outi = outu + (size_t)NU*OC;

  // workspace (ints): cnt[NN] | cur[NN] | off[NN] | part[2736] | nbr[2*NE]
  int* cnt  = (int*)d_ws;
  int* cur  = cnt + NN;
  int* off  = cur + NN;
  int* part = off + NN;
  int* nbr  = part + 2736;

  const int* er_src = er;        // users
  const int* er_dst = er + NE;   // items

  const int B = 256;
  const int NB1 = (NN + 255)/256;

  k_zero_i32<<<(2*NN + B - 1)/B, B, 0, stream>>>(cnt, 2*NN);
  k_deg<<<(NE + B - 1)/B, B, 0, stream>>>(er_src, er_dst, cnt);
  k_scan1<<<NB1, B, 0, stream>>>(cnt, off, part, NN);
  k_scan2<<<1, B, 0, stream>>>(part, NB1);
  k_scan3<<<NB1, B, 0, stream>>>(off, part, NN);
  k_scatter<<<(NE + B - 1)/B, B, 0, stream>>>(er_src, er_dst, off, cur, nbr);

  k_init_user<<<(NU + B - 1)/B, B, 0, stream>>>(user_ids, uemb, outu);
  k_init_item<<<(NI + 255)/256, 512, 0, stream>>>(prod_ids, iemb, feat, fW, fb, outi);

  // layer 1: items pull xu, users pull xp
  k_pull_fin<<<((size_t)NI*8 + B - 1)/B, B, 0, stream>>>(outi, NI, NU, outu, 0, 0, 32,
                                                 off, cnt, nbr, Wl_up1, bl_up1, Wr_up1);
  k_pull_fin<<<((size_t)NU*8 + B - 1)/B, B, 0, stream>>>(outu, NU, 0, outi, 0, 0, 32,
                                                 off, cnt, nbr, Wl_pu1, bl_pu1, Wr_pu1);
  // layer 2: items pull u1, users pull p1
  k_pull_fin<<<((size_t)NI*8 + B - 1)/B, B, 0, stream>>>(outi, NI, NU, outu, 32, 32, 64,
                                                 off, cnt, nbr, Wl_up2, bl_up2, Wr_up2);
  k_pull_fin<<<((size_t)NU*8 + B - 1)/B, B, 0, stream>>>(outu, NU, 0, outi, 32, 32, 64,
                                                 off, cnt, nbr, Wl_pu2, bl_pu2, Wr_pu2);
}